// Round 2
// baseline (1204.675 us; speedup 1.0000x reference)
//
#include <hip/hip_runtime.h>

#define NB 4096
#define NT 256
#define NH 64

// One wave (64 lanes) integrates one batch chain. Lane h owns hidden unit h.
// Weights in per-lane registers (~84 VGPRs). Layer2 broadcast via LDS
// uniform-address ds_read_b128 (conflict-free broadcast). Layer3 3-value
// reduction via DPP (VALU pipe) + readlane -> keeps the single LDS pipe
// from being the per-CU bottleneck (4 VALU pipes vs 1 LDS pipe).

template <int ctrl, int rm, int bm>
__device__ __forceinline__ float dpp_add(float v) {
    int m = __builtin_amdgcn_update_dpp(0, __builtin_bit_cast(int, v),
                                        ctrl, rm, bm, true);
    return v + __builtin_bit_cast(float, m);
}

// Full-wave (64-lane) sum -> uniform scalar via lane 63. All VALU-pipe.
__device__ __forceinline__ float wave_sum(float v) {
    v = dpp_add<0x111, 0xf, 0xf>(v); // row_shr:1
    v = dpp_add<0x112, 0xf, 0xf>(v); // row_shr:2
    v = dpp_add<0x114, 0xf, 0xe>(v); // row_shr:4
    v = dpp_add<0x118, 0xf, 0xc>(v); // row_shr:8
    v = dpp_add<0x142, 0xa, 0xf>(v); // row_bcast:15
    v = dpp_add<0x143, 0xc, 0xf>(v); // row_bcast:31
    return __builtin_bit_cast(float,
        __builtin_amdgcn_readlane(__builtin_bit_cast(int, v), 63));
}

__global__ __launch_bounds__(256) void tworeac_kernel(
    const float* __restrict__ u, const float* __restrict__ yseq,
    const float* __restrict__ useq, const float* __restrict__ W1,
    const float* __restrict__ b1, const float* __restrict__ W2,
    const float* __restrict__ b2, const float* __restrict__ W3,
    const float* __restrict__ b3, float* __restrict__ out)
{
    const int lane = threadIdx.x & 63;
    const int wave = threadIdx.x >> 6;
    const int b = blockIdx.x * 4 + wave;

    __shared__ float h1s[4][NH];

    // ---- weights into registers (lane owns hidden column h = lane) ----
    float w1x[3], w1y[9], w1u[3], w2r[NH], w3r[3];
    #pragma unroll
    for (int i = 0; i < 3; ++i) w1x[i] = W1[i * NH + lane];
    #pragma unroll
    for (int i = 0; i < 9; ++i) w1y[i] = W1[(3 + i) * NH + lane];
    #pragma unroll
    for (int i = 0; i < 3; ++i) w1u[i] = W1[(12 + i) * NH + lane];
    #pragma unroll
    for (int j = 0; j < NH; ++j) w2r[j] = W2[j * NH + lane];
    #pragma unroll
    for (int k = 0; k < 3; ++k) w3r[k] = W3[lane * 3 + k];
    const float b1h = b1[lane];
    const float b2h = b2[lane];
    const float b30 = b3[0], b31 = b3[1], b32 = b3[2];

    const float* ub  = u    + (size_t)b * NT;
    const float* ysb = yseq + (size_t)b * NT * 9;
    const float* usb = useq + (size_t)b * NT * 3;
    float*       ob  = out  + (size_t)b * NT * 3;

    float x0 = 0.f, x1 = 0.f, x2 = 0.f;

    float base1 = 0.f, ut = 0.f;
    auto rhs = [&](float xa, float xd, float xc,
                   float& d0, float& d1, float& d2) {
        // layer1: only the x-dependent part varies per RK stage
        float h1 = fmaf(xa, w1x[0], fmaf(xd, w1x[1], fmaf(xc, w1x[2], base1)));
        h1 = fmaxf(h1, 0.f);
        h1s[wave][lane] = h1;
        __builtin_amdgcn_wave_barrier();
        // layer2: acc = b2 + sum_j h1[j] * W2[j][lane]; 4 independent chains
        float a0 = 0.f, a1 = 0.f, a2 = 0.f, a3 = 0.f;
        #pragma unroll
        for (int j = 0; j < NH / 4; ++j) {
            float4 hv = *reinterpret_cast<const float4*>(&h1s[wave][4 * j]);
            a0 = fmaf(hv.x, w2r[4 * j + 0], a0);
            a1 = fmaf(hv.y, w2r[4 * j + 1], a1);
            a2 = fmaf(hv.z, w2r[4 * j + 2], a2);
            a3 = fmaf(hv.w, w2r[4 * j + 3], a3);
        }
        __builtin_amdgcn_wave_barrier();
        float h2 = fmaxf(b2h + ((a0 + a1) + (a2 + a3)), 0.f);
        // layer3: per-lane partials, DPP full-wave sums (uniform results)
        float s0 = wave_sum(h2 * w3r[0]);
        float s1 = wave_sum(h2 * w3r[1]);
        float s2 = wave_sum(h2 * w3r[2]);
        // _fg(x, u): K1=1, BETA=16, F=0.1, VR=1
        float s = sqrtf(fmaf(16.f, xa, 1.f));
        float r = 1.f / (1.f + s);
        d0 = (fmaf(0.1f, ut - xa, -xa)) + s0 + b30;
        d1 = fmaf(0.5f * xa * (s - 1.f), r, -0.1f * xd) + s1 + b31;
        d2 = (2.f * xa * r - 0.1f * xc) + s2 + b32;
    };

    for (int t = 0; t < NT; ++t) {
        // output = state at entry of step t
        if (lane < 3) ob[t * 3 + lane] = (lane == 0) ? x0 : (lane == 1 ? x1 : x2);

        ut = ub[t];
        base1 = b1h;
        #pragma unroll
        for (int i = 0; i < 9; ++i) base1 = fmaf(ysb[t * 9 + i], w1y[i], base1);
        #pragma unroll
        for (int i = 0; i < 3; ++i) base1 = fmaf(usb[t * 3 + i], w1u[i], base1);

        float k0, k1v, k2v, a0, a1, a2;
        rhs(x0, x1, x2, k0, k1v, k2v);                       // k1
        a0 = k0; a1 = k1v; a2 = k2v;
        rhs(fmaf(0.005f, k0, x0), fmaf(0.005f, k1v, x1),     // k2
            fmaf(0.005f, k2v, x2), k0, k1v, k2v);
        a0 = fmaf(2.f, k0, a0); a1 = fmaf(2.f, k1v, a1); a2 = fmaf(2.f, k2v, a2);
        rhs(fmaf(0.005f, k0, x0), fmaf(0.005f, k1v, x1),     // k3
            fmaf(0.005f, k2v, x2), k0, k1v, k2v);
        a0 = fmaf(2.f, k0, a0); a1 = fmaf(2.f, k1v, a1); a2 = fmaf(2.f, k2v, a2);
        rhs(fmaf(0.01f, k0, x0), fmaf(0.01f, k1v, x1),       // k4
            fmaf(0.01f, k2v, x2), k0, k1v, k2v);
        a0 += k0; a1 += k1v; a2 += k2v;

        const float c = 0.01f / 6.f;
        x0 = fmaf(c, a0, x0);
        x1 = fmaf(c, a1, x1);
        x2 = fmaf(c, a2, x2);
    }
}

extern "C" void kernel_launch(void* const* d_in, const int* in_sizes, int n_in,
                              void* d_out, int out_size, void* d_ws, size_t ws_size,
                              hipStream_t stream) {
    const float* u    = (const float*)d_in[0];
    const float* yseq = (const float*)d_in[1];
    const float* useq = (const float*)d_in[2];
    const float* W1   = (const float*)d_in[3];
    const float* b1   = (const float*)d_in[4];
    const float* W2   = (const float*)d_in[5];
    const float* b2   = (const float*)d_in[6];
    const float* W3   = (const float*)d_in[7];
    const float* b3   = (const float*)d_in[8];
    float* out = (float*)d_out;

    tworeac_kernel<<<NB / 4, 256, 0, stream>>>(u, yseq, useq, W1, b1, W2, b2,
                                               W3, b3, out);
}

// Round 3
// 1193.007 us; speedup vs baseline: 1.0098x; 1.0098x over previous
//
#include <hip/hip_runtime.h>

#define NB 4096
#define NT 256
#define NH 64

// One wave (64 lanes) integrates one batch chain. Lane h owns hidden unit h.
// Weights in per-lane registers (~85 VGPRs live). __launch_bounds__(256,4)
// raises the VGPR cap to 128 (4 waves/EU) so W2 stays in registers — the
// default heuristic capped at 64 VGPRs and spilled all of w2r to scratch
// (round-2 rocprof: VGPR_Count=64, dur 1277us, 3x the issue-count model).
// Layer2 broadcast via LDS uniform-address ds_read_b128 (conflict-free).
// Layer3 reduction via DPP (VALU pipe) + readlane, keeping the single LDS
// pipe well under the 4-VALU-pipe issue rate.

template <int ctrl, int rm, int bm>
__device__ __forceinline__ float dpp_add(float v) {
    int m = __builtin_amdgcn_update_dpp(0, __builtin_bit_cast(int, v),
                                        ctrl, rm, bm, true);
    return v + __builtin_bit_cast(float, m);
}

// Full-wave (64-lane) sum -> uniform scalar via lane 63. All VALU-pipe.
__device__ __forceinline__ float wave_sum(float v) {
    v = dpp_add<0x111, 0xf, 0xf>(v); // row_shr:1
    v = dpp_add<0x112, 0xf, 0xf>(v); // row_shr:2
    v = dpp_add<0x114, 0xf, 0xe>(v); // row_shr:4
    v = dpp_add<0x118, 0xf, 0xc>(v); // row_shr:8
    v = dpp_add<0x142, 0xa, 0xf>(v); // row_bcast:15
    v = dpp_add<0x143, 0xc, 0xf>(v); // row_bcast:31
    return __builtin_bit_cast(float,
        __builtin_amdgcn_readlane(__builtin_bit_cast(int, v), 63));
}

__global__ __launch_bounds__(256, 4) void tworeac_kernel(
    const float* __restrict__ u, const float* __restrict__ yseq,
    const float* __restrict__ useq, const float* __restrict__ W1,
    const float* __restrict__ b1, const float* __restrict__ W2,
    const float* __restrict__ b2, const float* __restrict__ W3,
    const float* __restrict__ b3, float* __restrict__ out)
{
    const int lane = threadIdx.x & 63;
    const int wave = threadIdx.x >> 6;
    const int b = blockIdx.x * 4 + wave;

    __shared__ float h1s[4][NH];

    // ---- weights into registers (lane owns hidden column h = lane) ----
    float w1x[3], w1y[9], w1u[3], w2r[NH], w3r[3];
    #pragma unroll
    for (int i = 0; i < 3; ++i) w1x[i] = W1[i * NH + lane];
    #pragma unroll
    for (int i = 0; i < 9; ++i) w1y[i] = W1[(3 + i) * NH + lane];
    #pragma unroll
    for (int i = 0; i < 3; ++i) w1u[i] = W1[(12 + i) * NH + lane];
    #pragma unroll
    for (int j = 0; j < NH; ++j) w2r[j] = W2[j * NH + lane];
    #pragma unroll
    for (int k = 0; k < 3; ++k) w3r[k] = W3[lane * 3 + k];
    const float b1h = b1[lane];
    const float b2h = b2[lane];
    const float b30 = b3[0], b31 = b3[1], b32 = b3[2];

    const float* ub  = u    + (size_t)b * NT;
    const float* ysb = yseq + (size_t)b * NT * 9;
    const float* usb = useq + (size_t)b * NT * 3;
    float*       ob  = out  + (size_t)b * NT * 3;

    float x0 = 0.f, x1 = 0.f, x2 = 0.f;

    float base1 = 0.f, ut = 0.f;
    auto rhs = [&](float xa, float xd, float xc,
                   float& d0, float& d1, float& d2) {
        // layer1: only the x-dependent part varies per RK stage
        float h1 = fmaf(xa, w1x[0], fmaf(xd, w1x[1], fmaf(xc, w1x[2], base1)));
        h1 = fmaxf(h1, 0.f);
        h1s[wave][lane] = h1;
        __builtin_amdgcn_wave_barrier();
        // layer2: acc = b2 + sum_j h1[j] * W2[j][lane]; 4 independent chains
        float a0 = 0.f, a1 = 0.f, a2 = 0.f, a3 = 0.f;
        #pragma unroll
        for (int j = 0; j < NH / 4; ++j) {
            float4 hv = *reinterpret_cast<const float4*>(&h1s[wave][4 * j]);
            a0 = fmaf(hv.x, w2r[4 * j + 0], a0);
            a1 = fmaf(hv.y, w2r[4 * j + 1], a1);
            a2 = fmaf(hv.z, w2r[4 * j + 2], a2);
            a3 = fmaf(hv.w, w2r[4 * j + 3], a3);
        }
        __builtin_amdgcn_wave_barrier();
        float h2 = fmaxf(b2h + ((a0 + a1) + (a2 + a3)), 0.f);
        // layer3: per-lane partials, DPP full-wave sums (uniform results)
        float s0 = wave_sum(h2 * w3r[0]);
        float s1 = wave_sum(h2 * w3r[1]);
        float s2 = wave_sum(h2 * w3r[2]);
        // _fg(x, u): K1=1, BETA=16, F=0.1, VR=1
        float s = sqrtf(fmaf(16.f, xa, 1.f));
        float r = 1.f / (1.f + s);
        d0 = (fmaf(0.1f, ut - xa, -xa)) + s0 + b30;
        d1 = fmaf(0.5f * xa * (s - 1.f), r, -0.1f * xd) + s1 + b31;
        d2 = (2.f * xa * r - 0.1f * xc) + s2 + b32;
    };

    for (int t = 0; t < NT; ++t) {
        // output = state at entry of step t
        if (lane < 3) ob[t * 3 + lane] = (lane == 0) ? x0 : (lane == 1 ? x1 : x2);

        ut = ub[t];
        base1 = b1h;
        #pragma unroll
        for (int i = 0; i < 9; ++i) base1 = fmaf(ysb[t * 9 + i], w1y[i], base1);
        #pragma unroll
        for (int i = 0; i < 3; ++i) base1 = fmaf(usb[t * 3 + i], w1u[i], base1);

        float k0, k1v, k2v, a0, a1, a2;
        rhs(x0, x1, x2, k0, k1v, k2v);                       // k1
        a0 = k0; a1 = k1v; a2 = k2v;
        rhs(fmaf(0.005f, k0, x0), fmaf(0.005f, k1v, x1),     // k2
            fmaf(0.005f, k2v, x2), k0, k1v, k2v);
        a0 = fmaf(2.f, k0, a0); a1 = fmaf(2.f, k1v, a1); a2 = fmaf(2.f, k2v, a2);
        rhs(fmaf(0.005f, k0, x0), fmaf(0.005f, k1v, x1),     // k3
            fmaf(0.005f, k2v, x2), k0, k1v, k2v);
        a0 = fmaf(2.f, k0, a0); a1 = fmaf(2.f, k1v, a1); a2 = fmaf(2.f, k2v, a2);
        rhs(fmaf(0.01f, k0, x0), fmaf(0.01f, k1v, x1),       // k4
            fmaf(0.01f, k2v, x2), k0, k1v, k2v);
        a0 += k0; a1 += k1v; a2 += k2v;

        const float c = 0.01f / 6.f;
        x0 = fmaf(c, a0, x0);
        x1 = fmaf(c, a1, x1);
        x2 = fmaf(c, a2, x2);
    }
}

extern "C" void kernel_launch(void* const* d_in, const int* in_sizes, int n_in,
                              void* d_out, int out_size, void* d_ws, size_t ws_size,
                              hipStream_t stream) {
    const float* u    = (const float*)d_in[0];
    const float* yseq = (const float*)d_in[1];
    const float* useq = (const float*)d_in[2];
    const float* W1   = (const float*)d_in[3];
    const float* b1   = (const float*)d_in[4];
    const float* W2   = (const float*)d_in[5];
    const float* b2   = (const float*)d_in[6];
    const float* W3   = (const float*)d_in[7];
    const float* b3   = (const float*)d_in[8];
    float* out = (float*)d_out;

    tworeac_kernel<<<NB / 4, 256, 0, stream>>>(u, yseq, useq, W1, b1, W2, b2,
                                               W3, b3, out);
}

// Round 4
// 1187.110 us; speedup vs baseline: 1.0148x; 1.0050x over previous
//
#include <hip/hip_runtime.h>

#define NB 4096
#define NT 256
#define NH 64

// One wave (64 lanes) integrates one batch chain. Lane h owns hidden unit h.
// Weights in per-lane registers (~85 VGPRs live).
//
// Round-3 lesson: __launch_bounds__(256,4) did NOT raise the VGPR budget —
// the backend still targeted 8 waves/EU (64 VGPR) and rematerialized w2r as
// per-use global loads (VGPR_Count=64, dur 1261us ~= 2.8x the issue model).
// Fix: amdgpu_waves_per_eu(4,4) makes max-occupancy=4 the target (budget
// 512/4=128 VGPRs), and an asm pin makes w2r opaque so remat is impossible.
//
// Layer2 broadcast via LDS uniform-address ds_read_b128 (conflict-free).
// Layer3 reduction via DPP (VALU pipe) + readlane, keeping the single LDS
// pipe well under the 4-VALU-pipe issue rate.

template <int ctrl, int rm, int bm>
__device__ __forceinline__ float dpp_add(float v) {
    int m = __builtin_amdgcn_update_dpp(0, __builtin_bit_cast(int, v),
                                        ctrl, rm, bm, true);
    return v + __builtin_bit_cast(float, m);
}

// Full-wave (64-lane) sum -> uniform scalar via lane 63. All VALU-pipe.
__device__ __forceinline__ float wave_sum(float v) {
    v = dpp_add<0x111, 0xf, 0xf>(v); // row_shr:1
    v = dpp_add<0x112, 0xf, 0xf>(v); // row_shr:2
    v = dpp_add<0x114, 0xf, 0xe>(v); // row_shr:4
    v = dpp_add<0x118, 0xf, 0xc>(v); // row_shr:8
    v = dpp_add<0x142, 0xa, 0xf>(v); // row_bcast:15
    v = dpp_add<0x143, 0xc, 0xf>(v); // row_bcast:31
    return __builtin_bit_cast(float,
        __builtin_amdgcn_readlane(__builtin_bit_cast(int, v), 63));
}

__global__ __attribute__((amdgpu_flat_work_group_size(256, 256),
                          amdgpu_waves_per_eu(4, 4)))
void tworeac_kernel(
    const float* __restrict__ u, const float* __restrict__ yseq,
    const float* __restrict__ useq, const float* __restrict__ W1,
    const float* __restrict__ b1, const float* __restrict__ W2,
    const float* __restrict__ b2, const float* __restrict__ W3,
    const float* __restrict__ b3, float* __restrict__ out)
{
    const int lane = threadIdx.x & 63;
    const int wave = threadIdx.x >> 6;
    const int b = blockIdx.x * 4 + wave;

    __shared__ float h1s[4][NH];

    // ---- weights into registers (lane owns hidden column h = lane) ----
    float w1x[3], w1y[9], w1u[3], w2r[NH], w3r[3];
    #pragma unroll
    for (int i = 0; i < 3; ++i) w1x[i] = W1[i * NH + lane];
    #pragma unroll
    for (int i = 0; i < 9; ++i) w1y[i] = W1[(3 + i) * NH + lane];
    #pragma unroll
    for (int i = 0; i < 3; ++i) w1u[i] = W1[(12 + i) * NH + lane];
    #pragma unroll
    for (int j = 0; j < NH; ++j) w2r[j] = W2[j * NH + lane];
    #pragma unroll
    for (int k = 0; k < 3; ++k) w3r[k] = W3[lane * 3 + k];
    // Pin w2r: values become opaque -> compiler cannot rematerialize them
    // as global loads inside the loop; with the 128-VGPR budget they stay
    // resident in registers.
    #pragma unroll
    for (int j = 0; j < NH; ++j) asm volatile("" : "+v"(w2r[j]));

    const float b1h = b1[lane];
    const float b2h = b2[lane];
    const float b30 = b3[0], b31 = b3[1], b32 = b3[2];

    const float* ub  = u    + (size_t)b * NT;
    const float* ysb = yseq + (size_t)b * NT * 9;
    const float* usb = useq + (size_t)b * NT * 3;
    float*       ob  = out  + (size_t)b * NT * 3;

    float x0 = 0.f, x1 = 0.f, x2 = 0.f;

    float base1 = 0.f, ut = 0.f;
    auto rhs = [&](float xa, float xd, float xc,
                   float& d0, float& d1, float& d2) {
        // layer1: only the x-dependent part varies per RK stage
        float h1 = fmaf(xa, w1x[0], fmaf(xd, w1x[1], fmaf(xc, w1x[2], base1)));
        h1 = fmaxf(h1, 0.f);
        h1s[wave][lane] = h1;
        __builtin_amdgcn_wave_barrier();
        // layer2: acc = b2 + sum_j h1[j] * W2[j][lane]; 4 independent chains
        float a0 = 0.f, a1 = 0.f, a2 = 0.f, a3 = 0.f;
        #pragma unroll
        for (int j = 0; j < NH / 4; ++j) {
            float4 hv = *reinterpret_cast<const float4*>(&h1s[wave][4 * j]);
            a0 = fmaf(hv.x, w2r[4 * j + 0], a0);
            a1 = fmaf(hv.y, w2r[4 * j + 1], a1);
            a2 = fmaf(hv.z, w2r[4 * j + 2], a2);
            a3 = fmaf(hv.w, w2r[4 * j + 3], a3);
        }
        __builtin_amdgcn_wave_barrier();
        float h2 = fmaxf(b2h + ((a0 + a1) + (a2 + a3)), 0.f);
        // layer3: per-lane partials, DPP full-wave sums (uniform results)
        float s0 = wave_sum(h2 * w3r[0]);
        float s1 = wave_sum(h2 * w3r[1]);
        float s2 = wave_sum(h2 * w3r[2]);
        // _fg(x, u): K1=1, BETA=16, F=0.1, VR=1
        float s = sqrtf(fmaf(16.f, xa, 1.f));
        float r = 1.f / (1.f + s);
        d0 = (fmaf(0.1f, ut - xa, -xa)) + s0 + b30;
        d1 = fmaf(0.5f * xa * (s - 1.f), r, -0.1f * xd) + s1 + b31;
        d2 = (2.f * xa * r - 0.1f * xc) + s2 + b32;
    };

    for (int t = 0; t < NT; ++t) {
        // output = state at entry of step t
        if (lane < 3) ob[t * 3 + lane] = (lane == 0) ? x0 : (lane == 1 ? x1 : x2);

        ut = ub[t];
        base1 = b1h;
        #pragma unroll
        for (int i = 0; i < 9; ++i) base1 = fmaf(ysb[t * 9 + i], w1y[i], base1);
        #pragma unroll
        for (int i = 0; i < 3; ++i) base1 = fmaf(usb[t * 3 + i], w1u[i], base1);

        float k0, k1v, k2v, a0, a1, a2;
        rhs(x0, x1, x2, k0, k1v, k2v);                       // k1
        a0 = k0; a1 = k1v; a2 = k2v;
        rhs(fmaf(0.005f, k0, x0), fmaf(0.005f, k1v, x1),     // k2
            fmaf(0.005f, k2v, x2), k0, k1v, k2v);
        a0 = fmaf(2.f, k0, a0); a1 = fmaf(2.f, k1v, a1); a2 = fmaf(2.f, k2v, a2);
        rhs(fmaf(0.005f, k0, x0), fmaf(0.005f, k1v, x1),     // k3
            fmaf(0.005f, k2v, x2), k0, k1v, k2v);
        a0 = fmaf(2.f, k0, a0); a1 = fmaf(2.f, k1v, a1); a2 = fmaf(2.f, k2v, a2);
        rhs(fmaf(0.01f, k0, x0), fmaf(0.01f, k1v, x1),       // k4
            fmaf(0.01f, k2v, x2), k0, k1v, k2v);
        a0 += k0; a1 += k1v; a2 += k2v;

        const float c = 0.01f / 6.f;
        x0 = fmaf(c, a0, x0);
        x1 = fmaf(c, a1, x1);
        x2 = fmaf(c, a2, x2);
    }
}

extern "C" void kernel_launch(void* const* d_in, const int* in_sizes, int n_in,
                              void* d_out, int out_size, void* d_ws, size_t ws_size,
                              hipStream_t stream) {
    const float* u    = (const float*)d_in[0];
    const float* yseq = (const float*)d_in[1];
    const float* useq = (const float*)d_in[2];
    const float* W1   = (const float*)d_in[3];
    const float* b1   = (const float*)d_in[4];
    const float* W2   = (const float*)d_in[5];
    const float* b2   = (const float*)d_in[6];
    const float* W3   = (const float*)d_in[7];
    const float* b3   = (const float*)d_in[8];
    float* out = (float*)d_out;

    tworeac_kernel<<<NB / 4, 256, 0, stream>>>(u, yseq, useq, W1, b1, W2, b2,
                                               W3, b3, out);
}